// Round 7
// baseline (400.276 us; speedup 1.0000x reference)
//
#include <hip/hip_runtime.h>
#include <hip/hip_fp16.h>

// Problem geometry: inputs (B=2, D=64, H=64, W=64, C=32) fp32, C innermost.
// Pass1: Sobel (VALID) -> mag = sqrt(gx^2+gy^2+gz^2) at 62^3 per (b,c)
// Pass2: Sobel on mag -> out = sqrt(gx^2+gy^2) + gz^2 at 60^3
// Result: mean(|out_pred - out_hr|) over 2*32*60^3 = 13,824,000 elems.
//
// R7: c4 thread mapping (4 channels/thread). All global loads are 16 B/lane
// (float4) in pass1 and 8 B/lane (uint2 = 4 x fp16) in pass2 -> wave-level
// VMEM instruction count halved, in-flight bytes per wave doubled, 1 KB
// contiguous per load instr. Tests the granularity/instr-cost hypothesis for
// the ~2.4 GB/ms plateau of R4-R6. Keeps z-streaming + rotation pipeline +
// wave-uniform row addressing. Pass2 YB=1 to fit fp32 partials in ~130 VGPR.

constexpr int BDIM = 256;
constexpr size_t IN_B = 8388608;   // 64*64*64*32 elements per batch
constexpr int IN_D = 131072;       // 64*64*32
constexpr int IN_H = 2048;         // 64*32
constexpr int M = 62;              // mag spatial dim
constexpr int F = 60;              // final spatial dim
constexpr int C = 32;
constexpr int MROW = M * C;                      // 1984
constexpr size_t MAGSZ = (size_t)M * M * MROW;   // halves per buffer
constexpr size_t PLANE = (size_t)M * MROW;       // halves per mag z-plane

union H2U { __half2 h; unsigned u; };

__device__ __forceinline__ float4 ld4(const float* p) {
    return *reinterpret_cast<const float4*>(p);
}
__device__ __forceinline__ float4 sm3(float4 a, float4 b, float4 c) {   // a+2b+c
    return make_float4(a.x + 2.f * b.x + c.x, a.y + 2.f * b.y + c.y,
                       a.z + 2.f * b.z + c.z, a.w + 2.f * b.w + c.w);
}
__device__ __forceinline__ float4 df2(float4 a, float4 c) {             // c-a
    return make_float4(c.x - a.x, c.y - a.y, c.z - a.z, c.w - a.w);
}
__device__ __forceinline__ float4 h4tof4(uint2 u) {
    H2U a, b; a.u = u.x; b.u = u.y;
    float2 l = __half22float2(a.h), h = __half22float2(b.h);
    return make_float4(l.x, l.y, h.x, h.y);
}

// ================= Pass 1: input -> fp16 magnitude, z-streamed =================
struct Raw1 { float4 v[12]; };                 // 4 rows x 3 x-taps, 4 ch
struct P1W  { float4 A[2], B[2], Cc[2]; };     // y-combined partials, 2 outputs

__device__ __forceinline__ void p1_issue(const float* __restrict__ pbase,
                                         int zplane, int y0, int lo, Raw1& r)
{
#pragma unroll
    for (int j = 0; j < 4; ++j) {
        const float* rowp = pbase + (size_t)zplane * IN_D + (size_t)(y0 + j) * IN_H;
        r.v[j * 3 + 0] = ld4(rowp + lo);
        r.v[j * 3 + 1] = ld4(rowp + lo + C);
        r.v[j * 3 + 2] = ld4(rowp + lo + 2 * C);
    }
}

__device__ __forceinline__ void p1_reduce(const Raw1& r, P1W& W)
{
    float4 SX[4], DX[4];
#pragma unroll
    for (int j = 0; j < 4; ++j) {
        SX[j] = sm3(r.v[j * 3], r.v[j * 3 + 1], r.v[j * 3 + 2]);
        DX[j] = df2(r.v[j * 3], r.v[j * 3 + 2]);
    }
#pragma unroll
    for (int k = 0; k < 2; ++k) {
        W.A[k]  = sm3(SX[k], SX[k + 1], SX[k + 2]);
        W.B[k]  = df2(SX[k], SX[k + 2]);
        W.Cc[k] = sm3(DX[k], DX[k + 1], DX[k + 2]);
    }
}

__device__ __forceinline__ void p1_emit(const P1W& W0, const P1W& W1, const P1W& W2,
                                        __half* __restrict__ mag, int z, int y0, int lo)
{
#pragma unroll
    for (int k = 0; k < 2; ++k) {
        float4 gx = df2(W0.A[k], W2.A[k]);
        float4 gy = sm3(W0.B[k], W1.B[k], W2.B[k]);
        float4 gz = sm3(W0.Cc[k], W1.Cc[k], W2.Cc[k]);
        float4 m = make_float4(sqrtf(gx.x * gx.x + gy.x * gy.x + gz.x * gz.x),
                               sqrtf(gx.y * gx.y + gy.y * gy.y + gz.y * gz.y),
                               sqrtf(gx.z * gx.z + gy.z * gy.z + gz.z * gz.z),
                               sqrtf(gx.w * gx.w + gy.w * gy.w + gz.w * gz.w));
        H2U o0, o1; o0.h = __floats2half2_rn(m.x, m.y); o1.h = __floats2half2_rn(m.z, m.w);
        *reinterpret_cast<uint2*>(mag + ((size_t)z * M + (y0 + k)) * MROW + lo)
            = make_uint2(o0.u, o1.u);
    }
}

__global__ __launch_bounds__(BDIM, 3) void sobel_mag_stream(
    const float* __restrict__ pred, const float* __restrict__ hr,
    __half* __restrict__ magbase, int bstart)
{
    const int xt = blockIdx.x & 1, yt = blockIdx.x >> 1;   // grid.x = 62 (2 x 31)
    const int zc = blockIdx.y;                             // [0,8): z-chunks of 8
    const int gz = blockIdx.z;                             // volume index
    const int b  = bstart + (gz >> 1);
    const float* __restrict__ in  = (gz & 1) ? hr : pred;
    __half*      __restrict__ mag = magbase + (size_t)gz * MAGSZ;

    const int y0 = yt * 2;                // outputs y0,y0+1; rows y0..y0+3 (<64)
    const int z0 = zc * 8;
    const int zn = min(8, M - z0);        // 8, last chunk 6
    const int x  = xt * 30 + (threadIdx.x >> 3);   // 0..31 / 30..61 (dup x=30,31 ok)
    const int lo = x * C + ((threadIdx.x & 7) << 2);

    const float* pbase = in + (size_t)b * IN_B;   // wave-uniform

    Raw1 r;
    P1W W0, W1, W2;
    p1_issue(pbase, z0 + 0, y0, lo, r); p1_reduce(r, W0);
    p1_issue(pbase, z0 + 1, y0, lo, r); p1_reduce(r, W1);
    p1_issue(pbase, z0 + 2, y0, lo, r); p1_reduce(r, W2);
    int z = 0;
    for (;;) {
        bool more = (z + 1 < zn);
        if (more) p1_issue(pbase, z0 + z + 3, y0, lo, r);
        p1_emit(W0, W1, W2, mag, z0 + z, y0, lo);
        if (!more) break;
        ++z;
        p1_reduce(r, W0);
        more = (z + 1 < zn);
        if (more) p1_issue(pbase, z0 + z + 3, y0, lo, r);
        p1_emit(W1, W2, W0, mag, z0 + z, y0, lo);
        if (!more) break;
        ++z;
        p1_reduce(r, W1);
        more = (z + 1 < zn);
        if (more) p1_issue(pbase, z0 + z + 3, y0, lo, r);
        p1_emit(W2, W0, W1, mag, z0 + z, y0, lo);
        if (!more) break;
        ++z;
        p1_reduce(r, W2);
    }
}

// ============ Pass 2: mag -> final, diff, partial sums, z-streamed ============
struct Raw2 { uint2 v[9]; };                   // 3 rows x 3 x-taps, 4 ch fp16
struct P2W  { float4 A, B, Cc; };              // YB=1

__device__ __forceinline__ void p2_issue(const __half* __restrict__ mbase,
                                         int zplane, int y0, int lo, Raw2& r)
{
#pragma unroll
    for (int j = 0; j < 3; ++j) {
        const __half* rowp = mbase + (size_t)zplane * PLANE + (size_t)(y0 + j) * MROW;
        r.v[j * 3 + 0] = *reinterpret_cast<const uint2*>(rowp + lo);
        r.v[j * 3 + 1] = *reinterpret_cast<const uint2*>(rowp + lo + C);
        r.v[j * 3 + 2] = *reinterpret_cast<const uint2*>(rowp + lo + 2 * C);
    }
}

__device__ __forceinline__ void p2_reduce(const Raw2& r, P2W& W)
{
    float4 SX[3], DX[3];
#pragma unroll
    for (int j = 0; j < 3; ++j) {
        float4 a = h4tof4(r.v[j * 3]);
        float4 b = h4tof4(r.v[j * 3 + 1]);
        float4 c = h4tof4(r.v[j * 3 + 2]);
        SX[j] = sm3(a, b, c);
        DX[j] = df2(a, c);
    }
    W.A  = sm3(SX[0], SX[1], SX[2]);
    W.B  = df2(SX[0], SX[2]);
    W.Cc = sm3(DX[0], DX[1], DX[2]);
}

__device__ __forceinline__ void p2_emit(const P2W& P0, const P2W& P1, const P2W& P2,
                                        const P2W& H0, const P2W& H1, const P2W& H2,
                                        float& acc)
{
    float4 gxP = df2(P0.A, P2.A);
    float4 gyP = sm3(P0.B, P1.B, P2.B);
    float4 gzP = sm3(P0.Cc, P1.Cc, P2.Cc);
    float4 gxH = df2(H0.A, H2.A);
    float4 gyH = sm3(H0.B, H1.B, H2.B);
    float4 gzH = sm3(H0.Cc, H1.Cc, H2.Cc);
    acc += fabsf((sqrtf(gxP.x * gxP.x + gyP.x * gyP.x) + gzP.x * gzP.x)
               - (sqrtf(gxH.x * gxH.x + gyH.x * gyH.x) + gzH.x * gzH.x));
    acc += fabsf((sqrtf(gxP.y * gxP.y + gyP.y * gyP.y) + gzP.y * gzP.y)
               - (sqrtf(gxH.y * gxH.y + gyH.y * gyH.y) + gzH.y * gzH.y));
    acc += fabsf((sqrtf(gxP.z * gxP.z + gyP.z * gyP.z) + gzP.z * gzP.z)
               - (sqrtf(gxH.z * gxH.z + gyH.z * gyH.z) + gzH.z * gzH.z));
    acc += fabsf((sqrtf(gxP.w * gxP.w + gyP.w * gyP.w) + gzP.w * gzP.w)
               - (sqrtf(gxH.w * gxH.w + gyH.w * gyH.w) + gzH.w * gzH.w));
}

__global__ __launch_bounds__(BDIM, 3) void sobel2_stream(
    const __half* __restrict__ magbase, float* __restrict__ partial, int bstart)
{
    const int xt = blockIdx.x & 1, yt = blockIdx.x >> 1;   // grid.x = 120 (2 x 60)
    const int zc = blockIdx.y;                             // [0,10): chunks of 6
    const int b  = bstart + blockIdx.z;
    const __half* __restrict__ magP = magbase + (size_t)(2 * blockIdx.z) * MAGSZ;
    const __half* __restrict__ magH = magP + MAGSZ;

    const int y0 = yt;                     // rows y0..y0+2 (< 62)
    const int z0 = zc * 6;
    const int zn = 6;
    const int xi = threadIdx.x >> 3;       // 0..31
    const int xraw = xt * 30 + xi;         // 0..31 / 30..61
    const bool xok = xi < 30;              // accumulate only x in [xt*30, xt*30+30)
    const int xload = min(xraw, F - 1);    // clamp loads (x-taps need x+2 <= 61)
    const int lo = xload * C + ((threadIdx.x & 7) << 2);

    Raw2 rp, rh;
    P2W P0, P1, P2, H0, H1, H2;
    p2_issue(magP, z0 + 0, y0, lo, rp); p2_issue(magH, z0 + 0, y0, lo, rh);
    p2_reduce(rp, P0); p2_reduce(rh, H0);
    p2_issue(magP, z0 + 1, y0, lo, rp); p2_issue(magH, z0 + 1, y0, lo, rh);
    p2_reduce(rp, P1); p2_reduce(rh, H1);
    p2_issue(magP, z0 + 2, y0, lo, rp); p2_issue(magH, z0 + 2, y0, lo, rh);
    p2_reduce(rp, P2); p2_reduce(rh, H2);

    float acc = 0.f;
    int z = 0;
    for (;;) {
        bool more = (z + 1 < zn);
        if (more) { p2_issue(magP, z0 + z + 3, y0, lo, rp);
                    p2_issue(magH, z0 + z + 3, y0, lo, rh); }
        if (xok) p2_emit(P0, P1, P2, H0, H1, H2, acc);
        if (!more) break;
        ++z;
        p2_reduce(rp, P0); p2_reduce(rh, H0);
        more = (z + 1 < zn);
        if (more) { p2_issue(magP, z0 + z + 3, y0, lo, rp);
                    p2_issue(magH, z0 + z + 3, y0, lo, rh); }
        if (xok) p2_emit(P1, P2, P0, H1, H2, H0, acc);
        if (!more) break;
        ++z;
        p2_reduce(rp, P1); p2_reduce(rh, H1);
        more = (z + 1 < zn);
        if (more) { p2_issue(magP, z0 + z + 3, y0, lo, rp);
                    p2_issue(magH, z0 + z + 3, y0, lo, rh); }
        if (xok) p2_emit(P2, P0, P1, H2, H0, H1, acc);
        if (!more) break;
        ++z;
        p2_reduce(rp, P2); p2_reduce(rh, H2);
    }

    // block reduction: wave64 shuffle, then across the 4 waves via LDS
    for (int o = 32; o > 0; o >>= 1) acc += __shfl_down(acc, o, 64);
    __shared__ float sred[BDIM / 64];
    const int lane = threadIdx.x & 63, wv = threadIdx.x >> 6;
    if (lane == 0) sred[wv] = acc;
    __syncthreads();
    if (threadIdx.x == 0) {
        float t = 0.f;
#pragma unroll
        for (int i = 0; i < BDIM / 64; ++i) t += sred[i];
        partial[(size_t)b * 1200 + (size_t)zc * 120 + blockIdx.x] = t;
    }
}

// -------- Finalize: sum 2400 partials in double, write mean --------
__global__ __launch_bounds__(BDIM) void finalize_kernel(
    const float* __restrict__ partial, float* __restrict__ out)
{
    double a = 0.0;
    for (int i = threadIdx.x; i < 2400; i += BDIM) a += (double)partial[i];
    for (int o = 32; o > 0; o >>= 1) a += __shfl_down(a, o, 64);
    __shared__ double sd[BDIM / 64];
    const int lane = threadIdx.x & 63, wv = threadIdx.x >> 6;
    if (lane == 0) sd[wv] = a;
    __syncthreads();
    if (threadIdx.x == 0) {
        double t = 0.0;
#pragma unroll
        for (int i = 0; i < BDIM / 64; ++i) t += sd[i];
        out[0] = (float)(t / 13824000.0);
    }
}

extern "C" void kernel_launch(void* const* d_in, const int* in_sizes, int n_in,
                              void* d_out, int out_size, void* d_ws, size_t ws_size,
                              hipStream_t stream)
{
    const float* pred = (const float*)d_in[0];
    const float* hr   = (const float*)d_in[1];

    // ws layout: [0, 9.6KB): 2400 float partials (fully overwritten each call)
    //            [64KB, ...): mag buffers fp16; 2 buffers (29.1 MiB) sequential,
    //            4 buffers (58.2 MiB) merged-batch if ws_size allows.
    float* partial = (float*)d_ws;
    __half* magbase = (__half*)((char*)d_ws + 65536);

    const bool merged = ws_size >= (size_t)65536 + 4 * MAGSZ * sizeof(__half);
    if (merged) {
        sobel_mag_stream<<<dim3(62, 8, 4), BDIM, 0, stream>>>(pred, hr, magbase, 0);
        sobel2_stream<<<dim3(120, 10, 2), BDIM, 0, stream>>>(magbase, partial, 0);
    } else {
        for (int b = 0; b < 2; ++b) {
            sobel_mag_stream<<<dim3(62, 8, 2), BDIM, 0, stream>>>(pred, hr, magbase, b);
            sobel2_stream<<<dim3(120, 10, 1), BDIM, 0, stream>>>(magbase, partial, b);
        }
    }
    finalize_kernel<<<1, BDIM, 0, stream>>>(partial, (float*)d_out);
}

// Round 8
// 288.416 us; speedup vs baseline: 1.3878x; 1.3878x over previous
//
#include <hip/hip_runtime.h>
#include <hip/hip_fp16.h>

// Problem geometry: inputs (B=2, D=64, H=64, W=64, C=32) fp32, C innermost.
// Pass1: Sobel (VALID) -> mag = sqrt(gx^2+gy^2+gz^2) at 62^3 per (b,c)
// Pass2: Sobel on mag -> out = sqrt(gx^2+gy^2) + gz^2 at 60^3
// Result: mean(|out_pred - out_hr|) over 2*32*60^3 = 13,824,000 elems.
//
// R8: LDS-staged z-streaming. R4-R7 plateaued at ~2.3 GB/ms with all pipes
// <40%: compute taps thrash L1 (48 KB plane set > 32 KB L1) so every tap is
// an L2-latency access. Now each z-step: block stages its slab into LDS with
// streaming coalesced float4 loads, syncs, computes taps from LDS (padded
// group stride 34/36 -> <=2-way bank aliasing, free), rotates z-partials in
// registers as R4. No launch_bounds minimums (R7 lesson: forced bounds +
// fat body = scratch spill catastrophe).

constexpr int BDIM = 256;
constexpr size_t IN_B = 8388608;   // 64*64*64*32 elements per batch
constexpr int IN_D = 131072;       // 64*64*32
constexpr int IN_H = 2048;         // 64*32
constexpr int M = 62;              // mag spatial dim
constexpr int F = 60;              // final spatial dim
constexpr int C = 32;
constexpr int MROW = M * C;                      // 1984
constexpr size_t MAGSZ = (size_t)M * M * MROW;   // halves per buffer
constexpr size_t PLANE = (size_t)M * MROW;       // halves per mag z-plane

// Pass1 LDS tile: 6 rows x 18 x-groups x 32 ch fp32, group stride 34 (pad 2)
constexpr int GS1 = 34;
constexpr int RS1 = 18 * GS1;      // 612 floats per row
// Pass2 LDS tile: 2 vols x 4 rows x 18 groups x 32 ch fp16, stride 36 (pad 4)
constexpr int GS2 = 36;
constexpr int RS2 = 18 * GS2;      // 648 halves per row
constexpr int VS2 = 4 * RS2;       // 2592 halves per volume

__device__ __forceinline__ float2 sm3(float2 a, float2 b, float2 c) {   // a+2b+c
    return make_float2(a.x + 2.f * b.x + c.x, a.y + 2.f * b.y + c.y);
}
__device__ __forceinline__ float2 df2(float2 a, float2 c) {             // c-a
    return make_float2(c.x - a.x, c.y - a.y);
}

// ================= Pass 1: input -> fp16 magnitude, LDS-staged =================
struct P1W { float2 A[4], B[4], Cc[4]; };

__device__ __forceinline__ void p1_stage(const float* __restrict__ pbase, int zp,
                                         int y0, int x0, float* __restrict__ lds,
                                         int tid)
{
    // 6 rows x 18 groups x 32 ch = 3456 floats = 864 float4
#pragma unroll
    for (int k = 0; k < 4; ++k) {
        int i = tid + k * BDIM;
        if (i < 864) {
            int row = i / 144;              // 144 float4 per row
            int rem = i - row * 144;
            int g   = rem >> 3;             // 8 float4 per group
            int off = (rem & 7) << 2;
            int ry  = min(y0 + row, 63);
            int gx  = min(x0 + g, 63);
            float4 v = *reinterpret_cast<const float4*>(
                pbase + (size_t)zp * IN_D + (size_t)ry * IN_H + gx * C + off);
            float* d = lds + row * RS1 + g * GS1 + off;   // 8-B aligned (pad=2)
            *reinterpret_cast<float2*>(d)     = make_float2(v.x, v.y);
            *reinterpret_cast<float2*>(d + 2) = make_float2(v.z, v.w);
        }
    }
}

__device__ __forceinline__ void p1_reduce(const float* __restrict__ lds,
                                          int xl, int cl, P1W& W)
{
    float2 SX[6], DX[6];
#pragma unroll
    for (int j = 0; j < 6; ++j) {
        const float* r = lds + j * RS1 + xl * GS1 + 2 * cl;
        float2 a = *reinterpret_cast<const float2*>(r);
        float2 b = *reinterpret_cast<const float2*>(r + GS1);
        float2 c = *reinterpret_cast<const float2*>(r + 2 * GS1);
        SX[j] = sm3(a, b, c);
        DX[j] = df2(a, c);
    }
#pragma unroll
    for (int k = 0; k < 4; ++k) {
        W.A[k]  = sm3(SX[k], SX[k + 1], SX[k + 2]);
        W.B[k]  = df2(SX[k], SX[k + 2]);
        W.Cc[k] = sm3(DX[k], DX[k + 1], DX[k + 2]);
    }
}

__device__ __forceinline__ void p1_emit(const P1W& W0, const P1W& W1, const P1W& W2,
                                        __half* __restrict__ mag, int z, int y0,
                                        int xo, int cl, int kmax, bool xok)
{
#pragma unroll
    for (int k = 0; k < 4; ++k) {
        if (k < kmax) {
            float2 gx = df2(W0.A[k], W2.A[k]);
            float2 gy = sm3(W0.B[k], W1.B[k], W2.B[k]);
            float2 gz = sm3(W0.Cc[k], W1.Cc[k], W2.Cc[k]);
            float mx = sqrtf(gx.x * gx.x + gy.x * gy.x + gz.x * gz.x);
            float my = sqrtf(gx.y * gx.y + gy.y * gy.y + gz.y * gz.y);
            if (xok)
                *reinterpret_cast<__half2*>(
                    mag + ((size_t)z * M + (y0 + k)) * MROW + xo * C + 2 * cl)
                    = __floats2half2_rn(mx, my);
        }
    }
}

__global__ __launch_bounds__(BDIM) void sobel_mag_lds(
    const float* __restrict__ pred, const float* __restrict__ hr,
    __half* __restrict__ magbase, int bstart)
{
    __shared__ float lds[6 * RS1];   // 14688 B

    const int xt = blockIdx.x & 3, yt = blockIdx.x >> 2;   // 4 x-tiles, 16 y-tiles
    const int zc = blockIdx.y;                             // [0,8): z-chunks of 8
    const int gz = blockIdx.z;
    const int b  = bstart + (gz >> 1);
    const float* __restrict__ in  = (gz & 1) ? hr : pred;
    __half*      __restrict__ mag = magbase + (size_t)gz * MAGSZ;

    const int x0 = xt * 16, y0 = yt * 4;
    const int z0 = zc * 8;
    const int zn = min(8, M - z0);          // 8, last chunk 6
    const int kmax = min(4, M - y0);        // 4, last y-tile 2
    const int tid = threadIdx.x;
    const int xl = tid >> 4;                // 0..15 x within tile
    const int cl = tid & 15;                // c2 lane
    const int xo = x0 + xl;
    const bool xok = xo < M;

    const float* pbase = in + (size_t)b * IN_B;

    P1W W0, W1, W2;
    p1_stage(pbase, z0 + 0, y0, x0, lds, tid);
    __syncthreads();
    p1_reduce(lds, xl, cl, W0);
    __syncthreads();
    p1_stage(pbase, z0 + 1, y0, x0, lds, tid);
    __syncthreads();
    p1_reduce(lds, xl, cl, W1);
    __syncthreads();

    int zi = 2;
    for (;;) {
        p1_stage(pbase, z0 + zi, y0, x0, lds, tid);
        __syncthreads();
        p1_reduce(lds, xl, cl, W2);
        __syncthreads();
        p1_emit(W0, W1, W2, mag, z0 + zi - 2, y0, xo, cl, kmax, xok);
        if (++zi >= zn + 2) break;

        p1_stage(pbase, z0 + zi, y0, x0, lds, tid);
        __syncthreads();
        p1_reduce(lds, xl, cl, W0);
        __syncthreads();
        p1_emit(W1, W2, W0, mag, z0 + zi - 2, y0, xo, cl, kmax, xok);
        if (++zi >= zn + 2) break;

        p1_stage(pbase, z0 + zi, y0, x0, lds, tid);
        __syncthreads();
        p1_reduce(lds, xl, cl, W1);
        __syncthreads();
        p1_emit(W2, W0, W1, mag, z0 + zi - 2, y0, xo, cl, kmax, xok);
        if (++zi >= zn + 2) break;
    }
}

// ============ Pass 2: mag -> final, diff, partial sums, LDS-staged ============
struct P2W { float2 A[2], B[2], Cc[2]; };

__device__ __forceinline__ void p2_stage(const __half* __restrict__ magP,
                                         const __half* __restrict__ magH,
                                         int zp, int y0, int x0,
                                         __half* __restrict__ lds, int tid)
{
    // 2 vols x 4 rows x 18 groups x 32 ch = 4608 halves = 1152 uint2
#pragma unroll
    for (int k = 0; k < 5; ++k) {
        int i = tid + k * BDIM;
        if (i < 1152) {
            int vol = (i >= 576) ? 1 : 0;
            int rem = i - vol * 576;
            int row = rem / 144;
            int rem2 = rem - row * 144;
            int g   = rem2 >> 3;
            int off = (rem2 & 7) << 2;      // halves
            const __half* src = (vol ? magH : magP)
                + (size_t)zp * PLANE + (size_t)(y0 + row) * MROW
                + min(x0 + g, M - 1) * C + off;
            uint2 v = *reinterpret_cast<const uint2*>(src);
            unsigned* d = reinterpret_cast<unsigned*>(
                lds + vol * VS2 + row * RS2 + g * GS2 + off);   // 4-B aligned
            d[0] = v.x; d[1] = v.y;
        }
    }
}

__device__ __forceinline__ void p2_reduce(const __half* __restrict__ lds,
                                          int xl, int cl, P2W& W)
{
    float2 SX[4], DX[4];
#pragma unroll
    for (int j = 0; j < 4; ++j) {
        const __half* r = lds + j * RS2 + xl * GS2 + 2 * cl;
        float2 a = __half22float2(*reinterpret_cast<const __half2*>(r));
        float2 b = __half22float2(*reinterpret_cast<const __half2*>(r + GS2));
        float2 c = __half22float2(*reinterpret_cast<const __half2*>(r + 2 * GS2));
        SX[j] = sm3(a, b, c);
        DX[j] = df2(a, c);
    }
#pragma unroll
    for (int k = 0; k < 2; ++k) {
        W.A[k]  = sm3(SX[k], SX[k + 1], SX[k + 2]);
        W.B[k]  = df2(SX[k], SX[k + 2]);
        W.Cc[k] = sm3(DX[k], DX[k + 1], DX[k + 2]);
    }
}

__device__ __forceinline__ void p2_emit(const P2W& P0, const P2W& P1, const P2W& P2,
                                        const P2W& H0, const P2W& H1, const P2W& H2,
                                        float& acc)
{
#pragma unroll
    for (int k = 0; k < 2; ++k) {
        float2 gxP = df2(P0.A[k], P2.A[k]);
        float2 gyP = sm3(P0.B[k], P1.B[k], P2.B[k]);
        float2 gzP = sm3(P0.Cc[k], P1.Cc[k], P2.Cc[k]);
        float2 gxH = df2(H0.A[k], H2.A[k]);
        float2 gyH = sm3(H0.B[k], H1.B[k], H2.B[k]);
        float2 gzH = sm3(H0.Cc[k], H1.Cc[k], H2.Cc[k]);
        float oPx = sqrtf(gxP.x * gxP.x + gyP.x * gyP.x) + gzP.x * gzP.x;
        float oPy = sqrtf(gxP.y * gxP.y + gyP.y * gyP.y) + gzP.y * gzP.y;
        float oHx = sqrtf(gxH.x * gxH.x + gyH.x * gyH.x) + gzH.x * gzH.x;
        float oHy = sqrtf(gxH.y * gxH.y + gyH.y * gyH.y) + gzH.y * gzH.y;
        acc += fabsf(oPx - oHx) + fabsf(oPy - oHy);
    }
}

__global__ __launch_bounds__(BDIM) void sobel2_lds(
    const __half* __restrict__ magbase, float* __restrict__ partial, int bstart)
{
    __shared__ __half lds[2 * VS2];   // 10368 B

    const int xt = blockIdx.x & 3, yt = blockIdx.x >> 2;   // 4 x-tiles, 30 y-tiles
    const int zc = blockIdx.y;                             // [0,10): chunks of 6
    const int b  = bstart + blockIdx.z;
    const __half* __restrict__ magP = magbase + (size_t)(2 * blockIdx.z) * MAGSZ;
    const __half* __restrict__ magH = magP + MAGSZ;

    const int x0 = xt * 16, y0 = yt * 2;
    const int z0 = zc * 6;
    const int tid = threadIdx.x;
    const int xl = tid >> 4;
    const int cl = tid & 15;
    const bool xok = (x0 + xl) < F;

    P2W P0, P1, P2, H0, H1, H2;
    p2_stage(magP, magH, z0 + 0, y0, x0, lds, tid);
    __syncthreads();
    p2_reduce(lds, xl, cl, P0); p2_reduce(lds + VS2, xl, cl, H0);
    __syncthreads();
    p2_stage(magP, magH, z0 + 1, y0, x0, lds, tid);
    __syncthreads();
    p2_reduce(lds, xl, cl, P1); p2_reduce(lds + VS2, xl, cl, H1);
    __syncthreads();

    float acc = 0.f;
    int zi = 2;
    for (;;) {
        p2_stage(magP, magH, z0 + zi, y0, x0, lds, tid);
        __syncthreads();
        p2_reduce(lds, xl, cl, P2); p2_reduce(lds + VS2, xl, cl, H2);
        __syncthreads();
        if (xok) p2_emit(P0, P1, P2, H0, H1, H2, acc);
        if (++zi >= 8) break;

        p2_stage(magP, magH, z0 + zi, y0, x0, lds, tid);
        __syncthreads();
        p2_reduce(lds, xl, cl, P0); p2_reduce(lds + VS2, xl, cl, H0);
        __syncthreads();
        if (xok) p2_emit(P1, P2, P0, H1, H2, H0, acc);
        if (++zi >= 8) break;

        p2_stage(magP, magH, z0 + zi, y0, x0, lds, tid);
        __syncthreads();
        p2_reduce(lds, xl, cl, P1); p2_reduce(lds + VS2, xl, cl, H1);
        __syncthreads();
        if (xok) p2_emit(P2, P0, P1, H2, H0, H1, acc);
        if (++zi >= 8) break;
    }

    // block reduction: wave64 shuffle, then across the 4 waves via LDS
    for (int o = 32; o > 0; o >>= 1) acc += __shfl_down(acc, o, 64);
    __shared__ float sred[BDIM / 64];
    const int lane = tid & 63, wv = tid >> 6;
    if (lane == 0) sred[wv] = acc;
    __syncthreads();
    if (tid == 0) {
        float t = 0.f;
#pragma unroll
        for (int i = 0; i < BDIM / 64; ++i) t += sred[i];
        partial[(size_t)b * 1200 + (size_t)zc * 120 + blockIdx.x] = t;
    }
}

// -------- Finalize: sum 2400 partials in double, write mean --------
__global__ __launch_bounds__(BDIM) void finalize_kernel(
    const float* __restrict__ partial, float* __restrict__ out)
{
    double a = 0.0;
    for (int i = threadIdx.x; i < 2400; i += BDIM) a += (double)partial[i];
    for (int o = 32; o > 0; o >>= 1) a += __shfl_down(a, o, 64);
    __shared__ double sd[BDIM / 64];
    const int lane = threadIdx.x & 63, wv = threadIdx.x >> 6;
    if (lane == 0) sd[wv] = a;
    __syncthreads();
    if (threadIdx.x == 0) {
        double t = 0.0;
#pragma unroll
        for (int i = 0; i < BDIM / 64; ++i) t += sd[i];
        out[0] = (float)(t / 13824000.0);
    }
}

extern "C" void kernel_launch(void* const* d_in, const int* in_sizes, int n_in,
                              void* d_out, int out_size, void* d_ws, size_t ws_size,
                              hipStream_t stream)
{
    const float* pred = (const float*)d_in[0];
    const float* hr   = (const float*)d_in[1];

    // ws layout: [0, 9.6KB): 2400 float partials (fully overwritten each call)
    //            [64KB, ...): mag buffers fp16; 2 buffers (29.1 MiB) sequential,
    //            4 buffers (58.2 MiB) merged-batch if ws_size allows.
    float* partial = (float*)d_ws;
    __half* magbase = (__half*)((char*)d_ws + 65536);

    const bool merged = ws_size >= (size_t)65536 + 4 * MAGSZ * sizeof(__half);
    if (merged) {
        sobel_mag_lds<<<dim3(64, 8, 4), BDIM, 0, stream>>>(pred, hr, magbase, 0);
        sobel2_lds<<<dim3(120, 10, 2), BDIM, 0, stream>>>(magbase, partial, 0);
    } else {
        for (int b = 0; b < 2; ++b) {
            sobel_mag_lds<<<dim3(64, 8, 2), BDIM, 0, stream>>>(pred, hr, magbase, b);
            sobel2_lds<<<dim3(120, 10, 1), BDIM, 0, stream>>>(magbase, partial, b);
        }
    }
    finalize_kernel<<<1, BDIM, 0, stream>>>(partial, (float*)d_out);
}